// Round 5
// baseline (226.461 us; speedup 1.0000x reference)
//
#include <hip/hip_runtime.h>
#include <stdint.h>

// InstanceHead on MI355X — f32/int32 inputs, f32 OUTPUT buffer (comparison is
// done in bf16 space by the harness; R2's inf-not-nan signature proves the
// buffer is native f32).  N=100000, M=256, B=8, L=128, D=64.
// NOTE: jnp.sort(axis=-1) on (N,1) is a NO-OP -> batch ids are UNSORTED.
// Valid centroids per row are SCATTERED; softmax stats scan all 256 columns
// with a batch-match filter, GEMM2 covers all 16 m-tiles.
// out = (normalize(feats@W+b) @ (conf*(cen_feats@W+b))^T) * softmax(-dist, batch-masked)

#define NN 100000
#define MM 256
#define BB 8
#define LL 128
#define DD 64
#define NTILES (NN / 16)  // 6250, exact

typedef float f32x4 __attribute__((ext_vector_type(4)));
typedef __bf16 bf16x8 __attribute__((ext_vector_type(8)));

union U16x8 { uint4 u; bf16x8 v; unsigned short s[8]; };

static __device__ __forceinline__ unsigned short f2bf(float f) {
  union { float f; unsigned int i; } t; t.f = f;
  unsigned int x = t.i;
  x += 0x7fffu + ((x >> 16) & 1u);  // round-to-nearest-even
  return (unsigned short)(x >> 16);
}

// ---------------- prep: cen (bf16), W^T (bf16), centroid meta ----------------
__global__ __launch_bounds__(256) void prep_kernel(
    const int* __restrict__ cen_coords,
    const float* __restrict__ cen_feats,
    const float* __restrict__ conf,
    const float* __restrict__ W,
    const float* __restrict__ bvec,
    unsigned short* __restrict__ cen_ws,   // [256][64] bf16
    unsigned short* __restrict__ wt_ws,    // [64][128] bf16 (W transposed)
    float4* __restrict__ cmeta_ws)         // [256] {batch, x, y, z}
{
  int tid = threadIdx.x;
  if (blockIdx.x < 16) {
    // cen rows: 16 rows per block, 16 threads per row, 4 cols per thread
    int m = blockIdx.x * 16 + (tid >> 4);
    int c = tid & 15;
    float a0 = 0.f, a1 = 0.f, a2 = 0.f, a3 = 0.f;
    for (int l = 0; l < LL; l++) {
      float f = cen_feats[m * LL + l];
      const float* wr = W + l * DD + c;
      a0 += f * wr[0];  a1 += f * wr[16];
      a2 += f * wr[32]; a3 += f * wr[48];
    }
    float cf = conf[m];
    cen_ws[m * DD + c +  0] = f2bf(cf * (a0 + bvec[c +  0]));
    cen_ws[m * DD + c + 16] = f2bf(cf * (a1 + bvec[c + 16]));
    cen_ws[m * DD + c + 32] = f2bf(cf * (a2 + bvec[c + 32]));
    cen_ws[m * DD + c + 48] = f2bf(cf * (a3 + bvec[c + 48]));
  } else {
    // block 16: transpose W (f32 -> bf16) + centroid meta
    for (int i = tid; i < LL * DD; i += 256) {
      int l = i >> 6, d = i & 63;
      wt_ws[d * LL + l] = f2bf(W[l * DD + d]);
    }
    {
      int4 cc = ((const int4*)cen_coords)[tid];  // tid < 256 == MM
      float4 f; f.x = (float)cc.x; f.y = (float)cc.y; f.z = (float)cc.z; f.w = (float)cc.w;
      cmeta_ws[tid] = f;
    }
  }
}

// ---------------- main: 1 wave per 16-row tile ----------------
__global__ __launch_bounds__(256) void main_kernel(
    const int* __restrict__ clu_coords,
    const float* __restrict__ feats,
    const float* __restrict__ bvec,
    const unsigned short* __restrict__ cen_ws,
    const unsigned short* __restrict__ wt_ws,
    const float4* __restrict__ cmeta_ws,
    float* __restrict__ out)
{
  __shared__ float4 cmeta_s[MM];
  __shared__ __align__(16) unsigned short clu_s[4][16 * 72];  // +8 pad: 2-way alias only
  __shared__ int4 rmeta_s[4][16];
  __shared__ float2 rsoft_s[4][16];

  int tid = threadIdx.x;
  int wave = tid >> 6, lane = tid & 63;
  for (int i = tid; i < MM; i += 256) cmeta_s[i] = cmeta_ws[i];
  int tile = blockIdx.x * 4 + wave;
  bool live = tile < NTILES;
  if (live && lane < 16) rmeta_s[wave][lane] = ((const int4*)clu_coords)[tile * 16 + lane];
  __syncthreads();

  int q = lane >> 4, c = lane & 15;
  float inv_nrm[4];
  if (live) {
    // ---- GEMM1: clu = feats @ W (+b).  A from global f32 feats (cvt->bf16),
    //      B from ws bf16 W^T (cache-resident).
    f32x4 acc[4] = {{0,0,0,0},{0,0,0,0},{0,0,0,0},{0,0,0,0}};
    const float4* fb = (const float4*)(feats + (size_t)(tile * 16 + c) * LL);
    const uint4* wb = (const uint4*)wt_ws;
#pragma unroll
    for (int ks = 0; ks < 4; ks++) {
      float4 f0 = fb[ks * 8 + q * 2];
      float4 f1 = fb[ks * 8 + q * 2 + 1];
      U16x8 a;
      a.s[0] = f2bf(f0.x); a.s[1] = f2bf(f0.y); a.s[2] = f2bf(f0.z); a.s[3] = f2bf(f0.w);
      a.s[4] = f2bf(f1.x); a.s[5] = f2bf(f1.y); a.s[6] = f2bf(f1.z); a.s[7] = f2bf(f1.w);
#pragma unroll
      for (int nt = 0; nt < 4; nt++) {
        U16x8 b; b.u = wb[(nt * 16 + c) * 16 + ks * 4 + q];
        acc[nt] = __builtin_amdgcn_mfma_f32_16x16x32_bf16(a.v, b.v, acc[nt], 0, 0, 0);
      }
    }
#pragma unroll
    for (int nt = 0; nt < 4; nt++) {
      float bv = bvec[nt * 16 + c];
      acc[nt][0] += bv; acc[nt][1] += bv; acc[nt][2] += bv; acc[nt][3] += bv;
    }
    // ---- row L2 norms: row r=q*4+reg lives across the 16 lanes of quad q
#pragma unroll
    for (int r = 0; r < 4; r++) {
      float s = acc[0][r]*acc[0][r] + acc[1][r]*acc[1][r] + acc[2][r]*acc[2][r] + acc[3][r]*acc[3][r];
      s += __shfl_xor(s, 1); s += __shfl_xor(s, 2); s += __shfl_xor(s, 4); s += __shfl_xor(s, 8);
      inv_nrm[r] = 1.0f / fmaxf(sqrtf(s), 1e-12f);
    }
    // ---- write (unnormalized) clu tile to LDS in bf16; norm folded into epilogue
#pragma unroll
    for (int nt = 0; nt < 4; nt++)
#pragma unroll
      for (int r = 0; r < 4; r++)
        clu_s[wave][(q * 4 + r) * 72 + nt * 16 + c] = f2bf(acc[nt][r]);

    // ---- per-row softmax stats: scan ALL 256 centroids, batch-match filter.
    //      4 lanes per row; lane ss handles m = ss, ss+4, ...
    {
      int rr = lane >> 2, ss = lane & 3;
      int4 rm = rmeta_s[wave][rr];
      float rbf = (float)rm.x;
      float x = (float)rm.y, y = (float)rm.z, z = (float)rm.w;
      float dmin = 3.4e38f;
      for (int m = ss; m < MM; m += 4) {
        float4 cm = cmeta_s[m];
        if (cm.x == rbf) {
          float dx = x - cm.y, dy = y - cm.z, dz = z - cm.w;
          float d = fmaxf(sqrtf(dx*dx + dy*dy + dz*dz), 0.1f);
          dmin = fminf(dmin, d);
        }
      }
      dmin = fminf(dmin, __shfl_xor(dmin, 1));
      dmin = fminf(dmin, __shfl_xor(dmin, 2));
      if (!(dmin < 3.0e38f)) dmin = 0.f;  // no same-batch centroid: keep finite
      float ssum = 0.f;
      for (int m = ss; m < MM; m += 4) {
        float4 cm = cmeta_s[m];
        if (cm.x == rbf) {
          float dx = x - cm.y, dy = y - cm.z, dz = z - cm.w;
          float d = fmaxf(sqrtf(dx*dx + dy*dy + dz*dz), 0.1f);
          ssum += __expf(dmin - d);
        }
      }
      ssum += __shfl_xor(ssum, 1);
      ssum += __shfl_xor(ssum, 2);
      float invden = ssum > 0.f ? 1.f / ssum : 0.f;
      rsoft_s[wave][rr] = make_float2(dmin, invden);  // 4 lanes same value: benign
    }
  }
  __syncthreads();
  if (!live) return;

  // ---- GEMM2 A-frags from LDS (layout transform done by the LDS round-trip)
  const uint4* cb = (const uint4*)(clu_s[wave]);
  U16x8 a0, a1;
  a0.u = cb[c * 9 + q];       // k = 0..31
  a1.u = cb[c * 9 + 4 + q];   // k = 32..63

  float rx[4], ry[4], rz[4], sdmin[4], sinv[4];
  int rb[4];
#pragma unroll
  for (int r = 0; r < 4; r++) {
    int4 rm = rmeta_s[wave][q * 4 + r];
    rb[r] = rm.x; rx[r] = (float)rm.y; ry[r] = (float)rm.z; rz[r] = (float)rm.w;
    float2 sp = rsoft_s[wave][q * 4 + r];
    sdmin[r] = sp.x; sinv[r] = sp.y;
  }

  const uint4* cenb = (const uint4*)cen_ws;
  size_t orow = (size_t)(tile * 16) * MM;
#pragma unroll
  for (int mt = 0; mt < 16; mt++) {  // ALL m-tiles: valid columns are scattered
    U16x8 b0, b1;
    b0.u = cenb[(mt * 16 + c) * 8 + q];
    b1.u = cenb[(mt * 16 + c) * 8 + 4 + q];
    f32x4 dacc = {0, 0, 0, 0};
    dacc = __builtin_amdgcn_mfma_f32_16x16x32_bf16(a0.v, b0.v, dacc, 0, 0, 0);
    dacc = __builtin_amdgcn_mfma_f32_16x16x32_bf16(a1.v, b1.v, dacc, 0, 0, 0);
    int m = mt * 16 + c;
    float4 cm = cmeta_s[m];
    int cbatch = (int)cm.x;
#pragma unroll
    for (int r = 0; r < 4; r++) {
      float dx = rx[r] - cm.y, dy = ry[r] - cm.z, dz = rz[r] - cm.w;
      float d = fmaxf(sqrtf(dx*dx + dy*dy + dz*dz), 0.1f);
      // clamp: only valid (same-batch) cols are guaranteed sdmin-d <= 0
      float w = __expf(fminf(sdmin[r] - d, 0.f)) * sinv[r] * inv_nrm[r];
      float val = (cbatch == rb[r]) ? dacc[r] * w : 0.f;
      out[orow + (size_t)(q * 4 + r) * MM + m] = val;  // f32 store
    }
  }
}

extern "C" void kernel_launch(void* const* d_in, const int* in_sizes, int n_in,
                              void* d_out, int out_size, void* d_ws, size_t ws_size,
                              hipStream_t stream) {
  const int* clu_coords = (const int*)d_in[0];
  const int* cen_coords = (const int*)d_in[1];
  const float* clu_feats = (const float*)d_in[2];
  const float* cen_feats = (const float*)d_in[3];
  const float* conf      = (const float*)d_in[4];
  const float* W         = (const float*)d_in[5];
  const float* bvec      = (const float*)d_in[6];
  float* out = (float*)d_out;

  char* ws = (char*)d_ws;
  unsigned short* cen_ws = (unsigned short*)ws;              // 32768 B
  unsigned short* wt_ws  = (unsigned short*)(ws + 32768);    // 16384 B
  float4* cmeta_ws       = (float4*)(ws + 32768 + 16384);    // 4096 B

  prep_kernel<<<17, 256, 0, stream>>>(cen_coords, cen_feats, conf, W, bvec,
                                      cen_ws, wt_ws, cmeta_ws);
  main_kernel<<<(NTILES + 3) / 4, 256, 0, stream>>>(
      clu_coords, clu_feats, bvec, cen_ws, wt_ws, cmeta_ws, out);
}